// Round 9
// baseline (5335.704 us; speedup 1.0000x reference)
//
#include <hip/hip_runtime.h>

#define DEVI __device__ __forceinline__
typedef unsigned long long u64;

// ---------------- problem constants ----------------
constexpr int B_ = 8, TE_ = 400, TD_ = 100, E_ = 128, H_ = 256;
constexpr int A_ = 612, V_ = 50000, VEXT_ = 50050;
constexpr int H4_ = 1024, H2_ = 512;
constexpr int NS_ = 16, SLW_ = 40;   // k4 a-slices: 15x40 + 1x12

// ---------------- workspace offsets (floats) ----------------
// tagged (u64-slot) regions: HBF/HBB ([2][2048] slots each), CHC ([2][8][512] slots)
constexpr size_t OFS_HBF  = 0;            // 8192 dwords (2 buf x 2048 slots x 2dw)
constexpr size_t OFS_HBB  = 8192;         // 8192
constexpr size_t OFS_CT   = 16384;        // [8][512] plain floats
constexpr size_t OFS_CHC  = 20480;        // 16384 dwords (2 x 4096 slots x 2dw)
constexpr size_t OFS_PG   = 36864;        // [100][8]
constexpr size_t OFS_SROW = 37664;        // [800]
constexpr size_t OFS_FLG  = 38464;        // 1024 u32 (k4 P0 full barrier)
constexpr size_t OFS_ATT  = 39488;        // [100][8][400]
constexpr size_t OFS_EO   = 359488;       // [8][400][512]
constexpr size_t OFS_OUTS = OFS_EO;       // alias (eo dead after k4c)
constexpr size_t OFS_EF   = OFS_EO + (size_t)B_*TE_*H2_;   // [8][400][612]

// ---------------- d_out scratch offsets (floats) -- dead before k5a ----------------
constexpr size_t DO_GDEC = 2ull*(size_t)TE_*B_*H4_;          // [100][8][1024]
constexpr size_t DO_XPRE = DO_GDEC + (size_t)TD_*B_*H4_;     // [100][8][128]
constexpr size_t DO_CTXH = DO_XPRE + (size_t)TD_*B_*E_;      // [100][8][512]
constexpr size_t DO_HCH  = DO_CTXH + (size_t)TD_*B_*H2_;     // [100][8][512] (h|c)
constexpr size_t DO_WCG  = DO_HCH + (size_t)TD_*B_*H2_;      // [512][1024]
constexpr size_t DO_EOWT = DO_WCG + (size_t)H2_*H4_;         // [8][1024][400]
constexpr size_t DO_EPB  = DO_EOWT + (size_t)B_*H4_*TE_;     // [8][400][16] TAGGED (x2dw)

// ---------------- helpers ----------------
#if defined(__has_builtin)
#if __has_builtin(__builtin_amdgcn_rcpf)
#define HAS_RCPF 1
#endif
#endif

DEVI float rcp_fast(float x) {
#ifdef HAS_RCPF
  return __builtin_amdgcn_rcpf(x);
#else
  return 1.0f / x;
#endif
}

DEVI float sigm(float x) { return rcp_fast(1.0f + __expf(-x)); }
DEVI float tanh_fast(float x) {
  float e = __expf(2.0f * x);
  return 1.0f - 2.0f * rcp_fast(e + 1.0f);
}

// ---- agent-coherent accesses ----
DEVI float ld_at(const float* p) {
  unsigned u = __hip_atomic_load((const unsigned*)p, __ATOMIC_RELAXED, __HIP_MEMORY_SCOPE_AGENT);
  return __uint_as_float(u);
}
DEVI u64 ld64_at(const u64* p) {
  return __hip_atomic_load(p, __ATOMIC_RELAXED, __HIP_MEMORY_SCOPE_AGENT);
}
DEVI void st64_at(u64* p, u64 v) {
  __hip_atomic_store(p, v, __ATOMIC_RELAXED, __HIP_MEMORY_SCOPE_AGENT);
}
DEVI u64 packft(float f, unsigned tag) {
  return (u64)__float_as_uint(f) | ((u64)tag << 32);
}
DEVI float lowf(u64 v) { return __uint_as_float((unsigned)v); }
DEVI unsigned hitag(u64 v) { return (unsigned)(v >> 32); }

DEVI float wave_max(float v) {
#pragma unroll
  for (int o = 32; o; o >>= 1) v = fmaxf(v, __shfl_xor(v, o));
  return v;
}
DEVI float wave_sum(float v) {
#pragma unroll
  for (int o = 32; o; o >>= 1) v += __shfl_xor(v, o);
  return v;
}

// flag-array grid barrier (only used once: k4 P0)
DEVI void flag_bar(unsigned* flags, int ncheck, int slot, unsigned ep, int stride) {
  __syncthreads();
  if (threadIdx.x == 0) {
    asm volatile("s_waitcnt vmcnt(0)" ::: "memory");
    __hip_atomic_store(&flags[slot * stride], ep, __ATOMIC_RELAXED, __HIP_MEMORY_SCOPE_AGENT);
  }
  if ((int)threadIdx.x < ncheck) {
    while (__hip_atomic_load(&flags[threadIdx.x * stride], __ATOMIC_RELAXED,
                             __HIP_MEMORY_SCOPE_AGENT) < ep) {
      __builtin_amdgcn_s_sleep(2);
    }
  }
  __syncthreads();
  asm volatile("" ::: "memory");
}

// =====================================================================
// K0: Wcg[512][1024] = Wx[128:640] @ Wih_d ; block(0,0) zeroes tagged
//     h-slots + flags (runs first on stream)
// =====================================================================
__global__ __launch_bounds__(256) void k0_wcg(
    const float* __restrict__ Wx, const float* __restrict__ Wih_d,
    float* __restrict__ dob, float* __restrict__ ws)
{
  __shared__ float AsT[32 * 64];
  __shared__ float Bsh[32 * 64];
  const float* Am = Wx + 128 * 128;
  float* C = dob + DO_WCG;
  const int ct = blockIdx.x, rt = blockIdx.y, tid = threadIdx.x;
  if (ct == 0 && rt == 0) {
    for (int i = tid; i < 16384; i += 256) ws[OFS_HBF + i] = 0.0f;   // HBF+HBB tagged slots
    unsigned* f = (unsigned*)(ws + OFS_FLG);
    for (int i = tid; i < 1024; i += 256) f[i] = 0u;
  }
  const int c0 = ct * 64, r0 = rt * 64;
  const int tx = tid & 15, ty = tid >> 4;
  float4 acc0 = make_float4(0,0,0,0), acc1 = acc0, acc2 = acc0, acc3 = acc0;
  for (int kc = 0; kc < 4; ++kc) {
#pragma unroll
    for (int i = 0; i < 2; ++i) {
      int q = tid * 2 + i;
      int r = q >> 3, kq = q & 7;
      float4 v = *(const float4*)&Am[(size_t)(r0 + r) * 128 + kc * 32 + kq * 4];
      AsT[(kq * 4 + 0) * 64 + r] = v.x; AsT[(kq * 4 + 1) * 64 + r] = v.y;
      AsT[(kq * 4 + 2) * 64 + r] = v.z; AsT[(kq * 4 + 3) * 64 + r] = v.w;
    }
#pragma unroll
    for (int i = 0; i < 2; ++i) {
      int q = tid * 2 + i;
      int kk = q >> 4, cq = q & 15;
      *(float4*)&Bsh[kk * 64 + cq * 4] =
          *(const float4*)&Wih_d[(size_t)(kc * 32 + kk) * H4_ + c0 + cq * 4];
    }
    __syncthreads();
#pragma unroll
    for (int kk = 0; kk < 32; ++kk) {
      float4 w4 = *(float4*)&Bsh[kk * 64 + tx * 4];
      const float* ar = &AsT[kk * 64 + ty * 4];
      acc0.x += ar[0]*w4.x; acc0.y += ar[0]*w4.y; acc0.z += ar[0]*w4.z; acc0.w += ar[0]*w4.w;
      acc1.x += ar[1]*w4.x; acc1.y += ar[1]*w4.y; acc1.z += ar[1]*w4.z; acc1.w += ar[1]*w4.w;
      acc2.x += ar[2]*w4.x; acc2.y += ar[2]*w4.y; acc2.z += ar[2]*w4.z; acc2.w += ar[2]*w4.w;
      acc3.x += ar[3]*w4.x; acc3.y += ar[3]*w4.y; acc3.z += ar[3]*w4.z; acc3.w += ar[3]*w4.w;
    }
    __syncthreads();
  }
  float4 r4[4] = {acc0, acc1, acc2, acc3};
#pragma unroll
  for (int i = 0; i < 4; ++i)
    *(float4*)&C[(size_t)(r0 + ty * 4 + i) * H4_ + c0 + tx * 4] = r4[i];
}

// =====================================================================
// K1d: decoder precompute: xpre[t]=emb@WxE+bx, gdec[t]=xpre@Wih_d+b_d
// =====================================================================
__global__ __launch_bounds__(256) void k1d_dec_pre(
    const int* __restrict__ dtok, const float* __restrict__ emb,
    const float* __restrict__ Wx, const float* __restrict__ bx,
    const float* __restrict__ Wih_d, const float* __restrict__ b_d,
    float* __restrict__ dob)
{
  __shared__ float er[8 * 128];
  __shared__ float xl[8 * 128];
  const int t = blockIdx.x, tid = threadIdx.x;
  for (int i = tid; i < 1024; i += 256) {
    int b = i >> 7, e = i & 127;
    er[i] = emb[(size_t)dtok[b * TD_ + t] * E_ + e];
  }
  __syncthreads();
  {
    const int col = tid & 127, bh = tid >> 7;
#pragma unroll
    for (int ii = 0; ii < 4; ++ii) {
      int b = bh + (ii << 1);
      float acc = bx[col];
      for (int k = 0; k < 128; ++k) acc += er[b * 128 + k] * Wx[(size_t)k * E_ + col];
      xl[b * 128 + col] = acc;
      dob[DO_XPRE + ((size_t)t * 8 + b) * E_ + col] = acc;
    }
  }
  __syncthreads();
  float bv[4];
#pragma unroll
  for (int g = 0; g < 4; ++g) bv[g] = b_d[g * H_ + tid];
  float af[32];
#pragma unroll
  for (int i = 0; i < 32; ++i) af[i] = bv[i & 3];
  for (int e = 0; e < E_; ++e) {
    float w[4];
#pragma unroll
    for (int g = 0; g < 4; ++g) w[g] = Wih_d[(size_t)e * H4_ + g * H_ + tid];
#pragma unroll
    for (int b = 0; b < 8; ++b) {
      float x = xl[b * 128 + e];
#pragma unroll
      for (int g = 0; g < 4; ++g) af[b * 4 + g] += x * w[g];
    }
  }
#pragma unroll
  for (int b = 0; b < 8; ++b)
#pragma unroll
    for (int g = 0; g < 4; ++g)
      dob[DO_GDEC + ((size_t)t * 8 + b) * H4_ + g * H_ + tid] = af[b * 4 + g];
}

// =====================================================================
// K2: encoder LSTM scans (fused input-gate, K=384). TAG-SYNC, no barrier:
//  h state = [2][2048] (float,tag) slots; read step t expects tag t,
//  write step t has tag t+1. Each block stages all 2048 slots -> dataflow
//  ordering makes buffer reuse safe.
// =====================================================================
__global__ __launch_bounds__(256, 1) void k2_encoder_scan(
    const int* __restrict__ etok, const float* __restrict__ emb,
    const float* __restrict__ Wih_f, const float* __restrict__ b_f,
    const float* __restrict__ Wih_b, const float* __restrict__ b_b,
    const float* __restrict__ Whh_f, const float* __restrict__ Whh_b,
    float* __restrict__ ws)
{
  __shared__ float sm[3072];        // [0,2048): h as [k][b]; [2048,3072): emb [b][128]
  __shared__ float part[2048];
  __shared__ int tokL[B_ * TE_];
  const int bid = blockIdx.x, tid = threadIdx.x;
  const int dir = bid >> 5, c0 = (bid & 31) * 8;
  const float* Whh = dir ? Whh_b : Whh_f;
  const float* Wih = dir ? Wih_b : Wih_f;
  const float* bbp = dir ? b_b : b_f;
  u64* hb = (u64*)(ws + (dir ? OFS_HBB : OFS_HBF));   // [2][2048] slots
  float* cT = ws + OFS_CT;
  float* eo = ws + OFS_EO;

  for (int i = tid; i < B_ * TE_; i += 256) tokL[i] = etok[i];

  const int jl = tid >> 3, kg = tid & 7;
  const int gt = jl >> 3, hcl = jl & 7;
  const int jcol = gt * H_ + c0 + hcl;
  float wreg[48];
#pragma unroll
  for (int kk = 0; kk < 48; ++kk) {
    if (kk < 32) wreg[kk] = Whh[(size_t)(kg + kk * 8) * H4_ + jcol];
    else         wreg[kk] = Wih[(size_t)(kg + (kk - 32) * 8) * H4_ + jcol];
  }
  const int uhc = tid >> 3, ub = tid & 7;
  float bias[4] = {0, 0, 0, 0};
  if (tid < 64) {
#pragma unroll
    for (int g = 0; g < 4; ++g) bias[g] = bbp[g * H_ + c0 + uhc];
  }
  const int ebb = tid >> 5, e4 = tid & 31;
  float c_reg = 0.0f;
  __syncthreads();

  for (int t = 0; t < TE_; ++t) {
    const int te = dir ? (TE_ - 1 - t) : t;
    // emb gather (plain, independent) — in flight during the poll
    float4 ev = *(const float4*)&emb[(size_t)tokL[ebb * TE_ + te] * E_ + e4 * 4];
    // tag-poll staging of full h state (8 slots/thread)
    {
      const u64* src = hb + (size_t)(t & 1) * 2048 + tid * 8;
      const unsigned want = (unsigned)t;
      u64 v[8];
      bool ok;
      do {
#pragma unroll
        for (int i = 0; i < 8; ++i) v[i] = ld64_at(src + i);
        ok = true;
#pragma unroll
        for (int i = 0; i < 8; ++i) ok &= (hitag(v[i]) == want);
        if (!ok) __builtin_amdgcn_s_sleep(1);
      } while (!ok);
#pragma unroll
      for (int i = 0; i < 8; ++i) sm[tid * 8 + i] = lowf(v[i]);
    }
    *(float4*)&sm[2048 + ebb * 128 + e4 * 4] = ev;
    __syncthreads();
    float acc[8] = {0, 0, 0, 0, 0, 0, 0, 0};
#pragma unroll
    for (int kk = 0; kk < 32; ++kk) {
      float w = wreg[kk];
      const float* hp = &sm[(kg + kk * 8) * 8];
#pragma unroll
      for (int b = 0; b < 8; ++b) acc[b] += hp[b] * w;
    }
#pragma unroll
    for (int kk = 32; kk < 48; ++kk) {
      float w = wreg[kk];
      const int e = kg + (kk - 32) * 8;
#pragma unroll
      for (int b = 0; b < 8; ++b) acc[b] += sm[2048 + b * 128 + e] * w;
    }
    *(float4*)&part[(jl * 8 + kg) * 8]     = make_float4(acc[0], acc[1], acc[2], acc[3]);
    *(float4*)&part[(jl * 8 + kg) * 8 + 4] = make_float4(acc[4], acc[5], acc[6], acc[7]);
    __syncthreads();
    if (tid < 64) {
      float g[4];
#pragma unroll
      for (int gg = 0; gg < 4; ++gg) {
        float s = bias[gg];
#pragma unroll
        for (int k2 = 0; k2 < 8; ++k2) s += part[((gg * 8 + uhc) * 8 + k2) * 8 + ub];
        g[gg] = s;
      }
      float ci = sigm(g[0]), cf = sigm(g[1]), cg = tanh_fast(g[2]), co = sigm(g[3]);
      c_reg = cf * c_reg + ci * cg;
      float hn = co * tanh_fast(c_reg);
      st64_at(&hb[(size_t)((t & 1) ^ 1) * 2048 + (c0 + uhc) * 8 + ub],
              packft(hn, (unsigned)(t + 1)));
      eo[((size_t)ub * TE_ + te) * H2_ + dir * H_ + c0 + uhc] = hn;
      if (t == TE_ - 1) cT[ub * H2_ + dir * H_ + c0 + uhc] = c_reg;
    }
  }
}

// =====================================================================
// K3: enc_feat = enc_out(3200,512) @ Wenc_feat(512,612) + benc_feat
// =====================================================================
__global__ __launch_bounds__(256) void k3_encfeat(
    const float* __restrict__ eo, const float* __restrict__ Wef,
    const float* __restrict__ bef, float* __restrict__ ef)
{
  __shared__ float AsT[32 * 64];
  __shared__ float Wsh[32 * 64];
  const int ct = blockIdx.x, rt = blockIdx.y, tid = threadIdx.x;
  const int c0 = ct * 64, r0 = rt * 64;
  const int tx = tid & 15, ty = tid >> 4;
  float4 acc0 = make_float4(0,0,0,0), acc1 = acc0, acc2 = acc0, acc3 = acc0;
  for (int kc = 0; kc < 16; ++kc) {
#pragma unroll
    for (int i = 0; i < 2; ++i) {
      int q = tid * 2 + i;
      int r = q >> 3, kq = q & 7;
      float4 v = *(const float4*)&eo[(size_t)(r0 + r) * H2_ + kc * 32 + kq * 4];
      AsT[(kq * 4 + 0) * 64 + r] = v.x; AsT[(kq * 4 + 1) * 64 + r] = v.y;
      AsT[(kq * 4 + 2) * 64 + r] = v.z; AsT[(kq * 4 + 3) * 64 + r] = v.w;
    }
#pragma unroll
    for (int i = 0; i < 2; ++i) {
      int q = tid * 2 + i;
      int kk = q >> 4, cq = q & 15;
      int col = c0 + cq * 4;
      float4 v = make_float4(0,0,0,0);
      if (col < A_) v = *(const float4*)&Wef[(size_t)(kc * 32 + kk) * A_ + col];
      *(float4*)&Wsh[kk * 64 + cq * 4] = v;
    }
    __syncthreads();
#pragma unroll
    for (int kk = 0; kk < 32; ++kk) {
      float4 w4 = *(float4*)&Wsh[kk * 64 + tx * 4];
      const float* ar = &AsT[kk * 64 + ty * 4];
      acc0.x += ar[0]*w4.x; acc0.y += ar[0]*w4.y; acc0.z += ar[0]*w4.z; acc0.w += ar[0]*w4.w;
      acc1.x += ar[1]*w4.x; acc1.y += ar[1]*w4.y; acc1.z += ar[1]*w4.z; acc1.w += ar[1]*w4.w;
      acc2.x += ar[2]*w4.x; acc2.y += ar[2]*w4.y; acc2.z += ar[2]*w4.z; acc2.w += ar[2]*w4.w;
      acc3.x += ar[3]*w4.x; acc3.y += ar[3]*w4.y; acc3.z += ar[3]*w4.z; acc3.w += ar[3]*w4.w;
    }
    __syncthreads();
  }
  const int col = c0 + tx * 4;
  if (col < A_) {
    float4 bb = *(const float4*)&bef[col];
    float4 r4[4] = {acc0, acc1, acc2, acc3};
#pragma unroll
    for (int i = 0; i < 4; ++i) {
      int row = r0 + ty * 4 + i;
      float4 o = make_float4(r4[i].x + bb.x, r4[i].y + bb.y, r4[i].z + bb.z, r4[i].w + bb.w);
      *(float4*)&ef[(size_t)row * A_ + col] = o;
    }
  }
}

// =====================================================================
// K3b: eoWT[b][j][te] = sum_k eo[b][te][k] * Wcg[k][j]
// =====================================================================
__global__ __launch_bounds__(256) void k3b_eowt(
    const float* __restrict__ eo, const float* __restrict__ dob_c, float* __restrict__ dob)
{
  __shared__ float Wt[32 * 64];
  __shared__ float Et[32 * 40];
  const float* Wcg = dob_c + DO_WCG;
  float* eoWT = dob + DO_EOWT;
  const int jt = blockIdx.x, tt = blockIdx.y, b = blockIdx.z, tid = threadIdx.x;
  const int j0 = jt * 64, te0 = tt * 40;
  const int j_l = tid & 63, tq = tid >> 6;
  float acc[10];
#pragma unroll
  for (int u = 0; u < 10; ++u) acc[u] = 0.0f;
  for (int kc = 0; kc < 16; ++kc) {
#pragma unroll
    for (int i = 0; i < 2; ++i) {
      int q = tid * 2 + i;
      int kk = q >> 4, j4 = q & 15;
      *(float4*)&Wt[kk * 64 + j4 * 4] =
          *(const float4*)&Wcg[(size_t)(kc * 32 + kk) * H4_ + j0 + j4 * 4];
    }
#pragma unroll
    for (int i = 0; i < 2; ++i) {
      int q = tid + i * 256;
      if (q < 320) {
        int te_l = q >> 3, kq = q & 7;
        float4 v = *(const float4*)&eo[((size_t)b * TE_ + te0 + te_l) * H2_ + kc * 32 + kq * 4];
        Et[(kq * 4 + 0) * 40 + te_l] = v.x; Et[(kq * 4 + 1) * 40 + te_l] = v.y;
        Et[(kq * 4 + 2) * 40 + te_l] = v.z; Et[(kq * 4 + 3) * 40 + te_l] = v.w;
      }
    }
    __syncthreads();
#pragma unroll
    for (int kk = 0; kk < 32; ++kk) {
      float w = Wt[kk * 64 + j_l];
      const float* ep2 = &Et[kk * 40 + tq * 10];
#pragma unroll
      for (int u = 0; u < 10; ++u) acc[u] += w * ep2[u];
    }
    __syncthreads();
  }
  float* outp = &eoWT[((size_t)b * H4_ + j0 + j_l) * TE_ + te0 + tq * 10];
#pragma unroll
  for (int u = 0; u < 10; ++u) outp[u] = acc[u];
}

// =====================================================================
// K4: decoder — 128 blocks x 512 thr, block=(b, s16). TAG-SYNC loop
//  (no barriers): chc = [2][8][512] tagged slots; epb = [8][400][16]
//  tagged slots. P1 expects chc tag t / epb tag t; P1 writes chc tag t+1;
//  P2 expects chc tag t+1, writes epb tag t+1.
// =====================================================================
__global__ __launch_bounds__(512, 1) void k4_decoder(
    const float* __restrict__ maskp,
    const float* __restrict__ Wred, const float* __restrict__ bred,
    const float* __restrict__ Whh_d,
    const float* __restrict__ Wdf, const float* __restrict__ bdf,
    const float* __restrict__ vvec, float* __restrict__ ws, float* __restrict__ dob)
{
  __shared__ float eoW[TE_ * 64];     // [te][jg] 102.4 KB
  __shared__ float eu[TE_];
  __shared__ float hcL[512];
  __shared__ float red[16];
  __shared__ float gdL[64];
  __shared__ float gl[64];
  __shared__ float pgl[64 * 9];
  __shared__ float prt[1280];
  __shared__ float dfl[48];
  __shared__ float bdfL[48];
  __shared__ float vvL[48];

  u64* chcU = (u64*)(ws + OFS_CHC);          // [2][8][512] slots
  float* att = ws + OFS_ATT;
  const float* efG = ws + OFS_EF;
  const u64* hbfU = (const u64*)(ws + OFS_HBF);   // buf0 = final fwd h (TE even)
  const u64* hbbU = (const u64*)(ws + OFS_HBB);
  const float* cT  = ws + OFS_CT;
  unsigned* flgF = (unsigned*)(ws + OFS_FLG) + 256;
  const float* gdec = dob + DO_GDEC;
  const float* eoWT = dob + DO_EOWT;
  u64* epbU = (u64*)(dob + DO_EPB);          // [8][400][16] slots
  float* hch = dob + DO_HCH;
  const int bid = blockIdx.x, tid = threadIdx.x;
  const int b = bid >> 4, s = bid & 15;
  const int a0 = s * SLW_, w = (s == 15) ? 12 : SLW_;
  const int nq = w >> 2;

  // ---- one-time fills: eoW LDS slice, Whh regs, vvec slice ----
  for (int i = tid; i < 64 * 100; i += 512) {
    int jgi = i / 100, c = i - jgi * 100;
    int jreal = (jgi >> 4) * 256 + s * 16 + (jgi & 15);
    float4 v = *(const float4*)&eoWT[((size_t)b * H4_ + jreal) * TE_ + c * 4];
    eoW[(c * 4 + 0) * 64 + jgi] = v.x;
    eoW[(c * 4 + 1) * 64 + jgi] = v.y;
    eoW[(c * 4 + 2) * 64 + jgi] = v.z;
    eoW[(c * 4 + 3) * 64 + jgi] = v.w;
  }
  const int jg = tid & 63, l8 = tid >> 6;
  const int jreal = (jg >> 4) * 256 + s * 16 + (jg & 15);
  float wreg[32];
#pragma unroll
  for (int kk = 0; kk < 32; ++kk)
    wreg[kk] = Whh_d[(size_t)(l8 + kk * 8) * H4_ + jreal];
  if (tid < w) vvL[tid] = vvec[a0 + tid];

  // ---- P0: tag clears; h0/c0 (blocks 0..31); Wdf[0] prefetch (32..127) ----
  if (tid < TE_) st64_at(&epbU[((size_t)b * TE_ + tid) * 16 + s], 0ULL);     // epb tags -> 0
  if (bid >= 32 && bid < 40) st64_at(&chcU[4096 + (bid - 32) * 512 + tid], 0ULL);  // chc buf1
  if (bid < 32) {
    const int isC = bid >> 4, pb = (bid >> 1) & 7, half = bid & 1;
    if (tid < 512)
      hcL[tid] = isC ? cT[pb * H2_ + tid]
                     : (tid < H_ ? lowf(ld64_at(hbfU + (size_t)tid * 8 + pb))
                                 : lowf(ld64_at(hbbU + (size_t)(tid - H_) * 8 + pb)));
    __syncthreads();
    {
      const int col_l = tid & 127, ks = tid >> 7;
      float acc = 0.0f;
      for (int kk = 0; kk < 128; ++kk) {
        int k = ks * 128 + kk;
        acc += hcL[k] * Wred[(size_t)k * H_ + half * 128 + col_l];
      }
      prt[ks * 128 + col_l] = acc;
    }
    __syncthreads();
    if (tid < 128) {
      float v2 = fmaxf(prt[tid] + prt[128 + tid] + prt[256 + tid] + prt[384 + tid] +
                       bred[half * 128 + tid], 0.0f);
      st64_at(&chcU[(size_t)pb * 512 + isC * 256 + half * 128 + tid], packft(v2, 0u));
    }
  } else {
    float dm = 0.0f;
#pragma unroll
    for (int i = 0; i < 7; ++i) {
      int f = (bid - 32) * 3264 + i * 512 + tid;
      if (i * 512 + tid < 3264 && f < H2_ * A_) dm += Wdf[f];
    }
    asm volatile("" :: "v"(dm));
  }
  flag_bar(flgF, 128, bid, 1, 2);

  float c_reg = 0.0f;
  if (tid < 16) c_reg = lowf(ld64_at(&chcU[(size_t)b * 512 + 256 + s * 16 + tid]));

  // ---- main loop (no barriers: tagged dataflow) ----
  for (int t = 0; t <= TD_; ++t) {

    // ===== P1 =====
    {
      // epb poll (tid<400, t>0): 16 slots/thread
      if (t > 0 && tid < TE_) {
        const u64* src = epbU + ((size_t)b * TE_ + tid) * 16;
        const unsigned want = (unsigned)t;
        u64 v[16];
        bool ok;
        do {
#pragma unroll
          for (int i = 0; i < 16; ++i) v[i] = ld64_at(src + i);
          ok = true;
#pragma unroll
          for (int i = 0; i < 16; ++i) ok &= (hitag(v[i]) == want);
          if (!ok) __builtin_amdgcn_s_sleep(1);
        } while (!ok);
        float sum = 0.0f;
#pragma unroll
        for (int i = 0; i < 16; ++i) sum += lowf(v[i]);
        eu[tid] = sum;
      }
      // h poll (tid in [400,464), t<TD_): 4 slots/thread of chc[t&1] h-part
      if (t < TD_ && tid >= 400 && tid < 464) {
        const int u = tid - 400;
        const u64* src = chcU + (size_t)(t & 1) * 4096 + b * 512 + u * 4;
        const unsigned want = (unsigned)t;
        u64 v[4];
        bool ok;
        do {
#pragma unroll
          for (int i = 0; i < 4; ++i) v[i] = ld64_at(src + i);
          ok = true;
#pragma unroll
          for (int i = 0; i < 4; ++i) ok &= (hitag(v[i]) == want);
          if (!ok) __builtin_amdgcn_s_sleep(1);
        } while (!ok);
#pragma unroll
        for (int i = 0; i < 4; ++i) hcL[u * 4 + i] = lowf(v[i]);
      }
      // gdec (plain, static) tid in [464,480)
      if (t < TD_ && tid >= 464 && tid < 480) {
        const int gi = tid - 464;
        float4 vgd = *(const float4*)&gdec[((size_t)t * 8 + b) * H4_ +
                                           (gi >> 2) * 256 + s * 16 + (gi & 3) * 4];
        *(float4*)&gdL[(gi >> 2) * 16 + (gi & 3) * 4] = vgd;
      }
      __syncthreads();

      float inv = 0.0f;
      if (t > 0) {
        float m = (tid < TE_) ? eu[tid] : -3.4e38f;
        m = wave_max(m);
        if ((tid & 63) == 0) red[tid >> 6] = m;
        __syncthreads();
        m = red[0];
#pragma unroll
        for (int i = 1; i < 8; ++i) m = fmaxf(m, red[i]);
        float u = 0.0f;
        if (tid < TE_) {
          u = __expf(eu[tid] - m) * maskp[b * TE_ + tid];
          eu[tid] = u;
        }
        float sl = wave_sum(u);
        if ((tid & 63) == 0) red[8 + (tid >> 6)] = sl;
        __syncthreads();
        float S = 0.0f;
#pragma unroll
        for (int i = 0; i < 8; ++i) S += red[8 + i];
        inv = rcp_fast(S);
      }

      if (t > 0 && tid < 25)
        att[((size_t)(t - 1) * 8 + b) * TE_ + s * 25 + tid] = eu[s * 25 + tid] * inv;

      if (t < TD_) {
        float accG = 0.0f, accW = 0.0f;
        if (t > 0) {
          for (int te = l8; te < TE_; te += 8)
            accG += eoW[te * 64 + jg] * eu[te];
        }
#pragma unroll
        for (int kk = 0; kk < 32; ++kk)
          accW += wreg[kk] * hcL[l8 + kk * 8];
        pgl[jg * 9 + l8] = accG * inv + accW;
        __syncthreads();
        if (tid < 64) {
          float sg = gdL[tid];
#pragma unroll
          for (int l = 0; l < 8; ++l) sg += pgl[tid * 9 + l];
          gl[tid] = sg;
        }
        __syncthreads();
        if (tid < 16) {
          float g0 = gl[tid], g1 = gl[16 + tid], g2 = gl[32 + tid], g3 = gl[48 + tid];
          float ci = sigm(g0), cf = sigm(g1), cg = tanh_fast(g2), co = sigm(g3);
          c_reg = cf * c_reg + ci * cg;
          float hn = co * tanh_fast(c_reg);
          int hc = s * 16 + tid;
          u64* dst = chcU + (size_t)((t + 1) & 1) * 4096 + b * 512;
          st64_at(&dst[hc], packft(hn, (unsigned)(t + 1)));
          st64_at(&dst[H_ + hc], packft(c_reg, (unsigned)(t + 1)));
          hch[((size_t)t * 8 + b) * H2_ + hc] = hn;
          hch[((size_t)t * 8 + b) * H2_ + H_ + hc] = c_reg;
        }
      }
    }
    if (t == TD_) break;

    // ===== P2: decf a-slice + e-partials =====
    {
      // poll full hc (tid<128): 4 slots/thread of chc[(t+1)&1], tag t+1
      if (tid < 128) {
        const u64* src = chcU + (size_t)((t + 1) & 1) * 4096 + b * 512 + tid * 4;
        const unsigned want = (unsigned)(t + 1);
        u64 v[4];
        bool ok;
        do {
#pragma unroll
          for (int i = 0; i < 4; ++i) v[i] = ld64_at(src + i);
          ok = true;
#pragma unroll
          for (int i = 0; i < 4; ++i) ok &= (hitag(v[i]) == want);
          if (!ok) __builtin_amdgcn_s_sleep(1);
        } while (!ok);
#pragma unroll
        for (int i = 0; i < 4; ++i) hcL[tid * 4 + i] = lowf(v[i]);
      }
      {
        const int maxc = (w + 3) >> 2;
        if (tid < maxc)
          *(float4*)&bdfL[tid * 4] = *(const float4*)&bdf[(size_t)t * A_ + a0 + tid * 4];
      }
      __syncthreads();

      // decf partials: (kq 32 x al 16), al<nq active
      const float* wp = Wdf + (size_t)t * H2_ * A_;
      {
        const int kq = tid >> 4, al = tid & 15;
        if (al < nq) {
          float4 a4 = make_float4(0, 0, 0, 0);
          const float* wpc = wp + a0 + al * 4;
#pragma unroll
          for (int i = 0; i < 16; ++i) {
            int k = kq * 16 + i;
            float4 w4 = *(const float4*)&wpc[(size_t)k * A_];
            float hv = hcL[k];
            a4.x += hv * w4.x; a4.y += hv * w4.y; a4.z += hv * w4.z; a4.w += hv * w4.w;
          }
          *(float4*)&prt[(kq * 10 + al) * 4] = a4;
        }
      }
      // narrow prefetch of Wdf[t+1]: rows b*64..+63 x own a-slice
      float dm = 0.0f;
      if (t + 1 < TD_) {
        const float* wp1 = Wdf + (size_t)(t + 1) * H2_ * A_;
#pragma unroll
        for (int q = 0; q < 2; ++q) {
          int f = tid + q * 512;
          if (f < 640) {
            int r = f / 10, c4 = f - r * 10;
            if (c4 < nq) {
              float4 vx = *(const float4*)&wp1[(size_t)(b * 64 + r) * A_ + a0 + c4 * 4];
              dm += vx.x + vx.y + vx.z + vx.w;
            }
          }
        }
      }
      __syncthreads();
      if (tid < w) {
        float ssum = bdfL[tid];
        const int c4 = tid >> 2, r = tid & 3;
#pragma unroll
        for (int kq = 0; kq < 32; ++kq) ssum += prt[(kq * 10 + c4) * 4 + r];
        dfl[tid] = ssum;
      }
      __syncthreads();

      // e-partials: thread te = tid (<400), tagged store
      if (tid < TE_) {
        const float* efp = &efG[((size_t)b * TE_ + tid) * A_ + a0];
        float acc = 0.0f;
        for (int q = 0; q < nq; ++q) {
          float4 e4 = *(const float4*)&efp[q * 4];
          const float* dd = &dfl[q * 4];
          const float* vv = &vvL[q * 4];
          acc += vv[0] * tanh_fast(e4.x + dd[0]);
          acc += vv[1] * tanh_fast(e4.y + dd[1]);
          acc += vv[2] * tanh_fast(e4.z + dd[2]);
          acc += vv[3] * tanh_fast(e4.w + dd[3]);
        }
        st64_at(&epbU[((size_t)b * TE_ + tid) * 16 + s], packft(acc, (unsigned)(t + 1)));
      }
      asm volatile("" :: "v"(dm));
    }
  }
}

// =====================================================================
// K4c: ctxh[t][b][d] = sum_te att[t][b][te] * eo[b][te][d]
// =====================================================================
__global__ __launch_bounds__(256) void k4c_ctx(
    const float* __restrict__ ws, float* __restrict__ dob)
{
  __shared__ float AsT[32 * 64];
  __shared__ float Bsh[32 * 64];
  const float* att = ws + OFS_ATT;
  const float* eo  = ws + OFS_EO;
  float* ctxh = dob + DO_CTXH;
  const int ct = blockIdx.x, rt = blockIdx.y, b = blockIdx.z, tid = threadIdx.x;
  const int c0 = ct * 64, r0 = rt * 64;
  const int tx = tid & 15, ty = tid >> 4;
  float4 acc0 = make_float4(0,0,0,0), acc1 = acc0, acc2 = acc0, acc3 = acc0;
  for (int kc = 0; kc < 13; ++kc) {
#pragma unroll
    for (int i = 0; i < 2; ++i) {
      int q = tid * 2 + i;
      int r = q >> 3, kq = q & 7;
      int k = kc * 32 + kq * 4;
      float4 v = make_float4(0, 0, 0, 0);
      if (k < TE_ && r0 + r < TD_)
        v = *(const float4*)&att[((size_t)(r0 + r) * 8 + b) * TE_ + k];
      AsT[(kq * 4 + 0) * 64 + r] = v.x; AsT[(kq * 4 + 1) * 64 + r] = v.y;
      AsT[(kq * 4 + 2) * 64 + r] = v.z; AsT[(kq * 4 + 3) * 64 + r] = v.w;
    }
#pragma unroll
    for (int i = 0; i < 2; ++i) {
      int q = tid * 2 + i;
      int kk = q >> 4, cq = q & 15;
      int k = kc * 32 + kk;
      float4 v = make_float4(0, 0, 0, 0);
      if (k < TE_) v = *(const float4*)&eo[((size_t)b * TE_ + k) * H2_ + c0 + cq * 4];
      *(float4*)&Bsh[kk * 64 + cq * 4] = v;
    }
    __syncthreads();
#pragma unroll
    for (int kk = 0; kk < 32; ++kk) {
      float4 w4 = *(float4*)&Bsh[kk * 64 + tx * 4];
      const float* ar = &AsT[kk * 64 + ty * 4];
      acc0.x += ar[0]*w4.x; acc0.y += ar[0]*w4.y; acc0.z += ar[0]*w4.z; acc0.w += ar[0]*w4.w;
      acc1.x += ar[1]*w4.x; acc1.y += ar[1]*w4.y; acc1.z += ar[1]*w4.z; acc1.w += ar[1]*w4.w;
      acc2.x += ar[2]*w4.x; acc2.y += ar[2]*w4.y; acc2.z += ar[2]*w4.z; acc2.w += ar[2]*w4.w;
      acc3.x += ar[3]*w4.x; acc3.y += ar[3]*w4.y; acc3.z += ar[3]*w4.z; acc3.w += ar[3]*w4.w;
    }
    __syncthreads();
  }
  float4 r4[4] = {acc0, acc1, acc2, acc3};
#pragma unroll
  for (int i = 0; i < 4; ++i) {
    int row = r0 + ty * 4 + i;
    if (row < TD_)
      *(float4*)&ctxh[((size_t)row * 8 + b) * H2_ + c0 + tx * 4] = r4[i];
  }
}

// =====================================================================
// K4b: batched post-pass: x_t, outs_t, p_gen_t for all t (grid 100)
// =====================================================================
__global__ __launch_bounds__(256) void k4b_post(
    const float* __restrict__ Wx, const float* __restrict__ Wout, const float* __restrict__ bout,
    const float* __restrict__ Wpg, const float* __restrict__ bpg,
    float* __restrict__ ws, const float* __restrict__ dob)
{
  __shared__ float hcl[4096], ctxl[4096], cpl[4096], xl[1024], red2[256];
  const int t = blockIdx.x, tid = threadIdx.x;
  const float* hch  = dob + DO_HCH;
  const float* ctxh = dob + DO_CTXH;
  const float* xpre = dob + DO_XPRE;
  for (int i = tid; i < 4096; i += 256) {
    hcl[i]  = hch[(size_t)t * 4096 + i];
    ctxl[i] = ctxh[(size_t)t * 4096 + i];
    cpl[i]  = t ? ctxh[(size_t)(t - 1) * 4096 + i] : 0.0f;
  }
  __syncthreads();
  {
    const int col = tid & 127, bh = tid >> 7;
#pragma unroll
    for (int ii = 0; ii < 4; ++ii) {
      int b = bh + (ii << 1);
      float acc = xpre[(size_t)t * 1024 + b * E_ + col];
      for (int k = 0; k < H2_; ++k) acc += cpl[b * H2_ + k] * Wx[(size_t)(128 + k) * E_ + col];
      xl[b * E_ + col] = acc;
    }
  }
  __syncthreads();
  {
    const int col = tid;
    for (int b = 0; b < 8; ++b) {
      float acc = bout[col];
      for (int k = 0; k < 768; ++k)
        acc += (k < H_ ? hcl[b * H2_ + k] : ctxl[b * H2_ + (k - H_)]) * Wout[(size_t)k * H_ + col];
      ws[OFS_OUTS + ((size_t)t * 8 + b) * H_ + col] = acc;
    }
  }
  {
    const int b = tid >> 5, sg = tid & 31;
    float acc = 0.0f;
    for (int j = 0; j < 36; ++j) {
      int k = sg * 36 + j;
      float xv;
      if (k < H2_)       xv = ctxl[b * H2_ + k];
      else if (k < 768)  xv = hcl[b * H2_ + (k - H2_)];
      else if (k < 1024) xv = hcl[b * H2_ + H_ + (k - 768)];
      else               xv = xl[b * E_ + (k - 1024)];
      acc += xv * Wpg[k];
    }
    red2[tid] = acc;
    __syncthreads();
    if (tid < 8) {
      float s = 0.0f;
      for (int k2 = 0; k2 < 32; ++k2) s += red2[tid * 32 + k2];
      ws[OFS_PG + t * 8 + tid] = sigm(s + bpg[0]);
    }
  }
}

// =====================================================================
// K5a: logits = outs(800,256) @ Wv(256,50000) + bv -> d_out
// =====================================================================
__global__ __launch_bounds__(256) void k5a_logits(
    const float* __restrict__ outs, const float* __restrict__ Wv,
    const float* __restrict__ bv, float* __restrict__ out)
{
  __shared__ float aT[32 * 64];
  __shared__ float wl[32 * 256];
  const int rt = blockIdx.x, ct = blockIdx.y, tid = threadIdx.x;
  const int r0 = rt * 64, c0 = ct * 256;
  const int cq = tid & 63, rg = tid >> 6;
  float4 acc[16];
#pragma unroll
  for (int i = 0; i < 16; ++i) acc[i] = make_float4(0, 0, 0, 0);
  for (int kc = 0; kc < 8; ++kc) {
#pragma unroll
    for (int i = 0; i < 2; ++i) {
      int q = tid * 2 + i;
      int r = q >> 3, kq = q & 7;
      float4 v = make_float4(0, 0, 0, 0);
      if (r0 + r < 800) v = *(const float4*)&outs[(size_t)(r0 + r) * H_ + kc * 32 + kq * 4];
      aT[(kq * 4 + 0) * 64 + r] = v.x; aT[(kq * 4 + 1) * 64 + r] = v.y;
      aT[(kq * 4 + 2) * 64 + r] = v.z; aT[(kq * 4 + 3) * 64 + r] = v.w;
    }
#pragma unroll
    for (int i = 0; i < 8; ++i) {
      int q = tid + i * 256;
      int kk = q >> 6, c4 = q & 63;
      int col = c0 + c4 * 4;
      float4 v = make_float4(0, 0, 0, 0);
      if (col < V_) v = *(const float4*)&Wv[(size_t)(kc * 32 + kk) * V_ + col];
      *(float4*)&wl[kk * 256 + c4 * 4] = v;
    }
    __syncthreads();
#pragma unroll
    for (int kk = 0; kk < 32; ++kk) {
      float4 w4 = *(float4*)&wl[kk * 256 + cq * 4];
      const float* ar = &aT[kk * 64 + rg * 16];
#pragma unroll
      for (int rr = 0; rr < 16; ++rr) {
        float a = ar[rr];
        acc[rr].x += a * w4.x; acc[rr].y += a * w4.y;
        acc[rr].z += a * w4.z; acc[rr].w += a * w4.w;
      }
    }
    __syncthreads();
  }
  const int col = c0 + cq * 4;
  if (col < V_) {
    float4 bb = *(const float4*)&bv[col];
#pragma unroll
    for (int rr = 0; rr < 16; ++rr) {
      int row = r0 + rg * 16 + rr;
      if (row < 800) {
        float2 lo = make_float2(acc[rr].x + bb.x, acc[rr].y + bb.y);
        float2 hi = make_float2(acc[rr].z + bb.z, acc[rr].w + bb.w);
        *(float2*)&out[(size_t)row * VEXT_ + col] = lo;
        *(float2*)&out[(size_t)row * VEXT_ + col + 2] = hi;
      }
    }
  }
}

// K5b: per-row sum of exp(logit)
__global__ __launch_bounds__(256) void k5b_rowsum(const float* __restrict__ out, float* __restrict__ Srow)
{
  __shared__ float red[256];
  const int r = blockIdx.x, tid = threadIdx.x;
  const float* base = out + (size_t)r * VEXT_;
  float s = 0.0f;
  for (int i = tid; i < V_ / 2; i += 256) {
    float2 v = *(const float2*)&base[i * 2];
    s += __expf(v.x) + __expf(v.y);
  }
  red[tid] = s; __syncthreads();
  for (int st = 128; st > 0; st >>= 1) { if (tid < st) red[tid] += red[tid + st]; __syncthreads(); }
  if (tid == 0) Srow[r] = red[0];
}

// K5c: in-place final = pgen * exp(logit)/S ; zero OOV tail
__global__ __launch_bounds__(256) void k5c_final(
    float* __restrict__ out, const float* __restrict__ Srow, const float* __restrict__ pg)
{
  const int cc = blockIdx.x, r = blockIdx.y, tid = threadIdx.x;
  const float scale = pg[r] * rcp_fast(Srow[r]);
  float* base = out + (size_t)r * VEXT_;
#pragma unroll
  for (int i = 0; i < 4; ++i) {
    int col = cc * 2048 + i * 512 + tid * 2;
    if (col < V_) {
      float2 v = *(float2*)&base[col];
      v.x = __expf(v.x) * scale; v.y = __expf(v.y) * scale;
      *(float2*)&base[col] = v;
    } else if (col < VEXT_) {
      *(float2*)&base[col] = make_float2(0.0f, 0.0f);
    }
  }
}

// K5d: scatter copy distribution
__global__ __launch_bounds__(256) void k5d_scatter(
    float* __restrict__ out, const float* __restrict__ ws, const int* __restrict__ ext)
{
  const int r = blockIdx.x, tid = threadIdx.x;
  const int b = r & 7;
  const float* at = ws + OFS_ATT + (size_t)r * TE_;
  const float w = 1.0f - ws[OFS_PG + r];
  float* base = out + (size_t)r * VEXT_;
  for (int i = tid; i < TE_; i += 256)
    atomicAdd(&base[ext[b * TE_ + i]], w * at[i]);
}

// =====================================================================
extern "C" void kernel_launch(void* const* d_in, const int* in_sizes, int n_in,
                              void* d_out, int out_size, void* d_ws, size_t ws_size,
                              hipStream_t stream) {
  const int*   etok  = (const int*)d_in[0];
  const int*   dtok  = (const int*)d_in[1];
  const int*   ext   = (const int*)d_in[2];
  const float* maskp = (const float*)d_in[3];
  const float* emb   = (const float*)d_in[4];
  const float* Wih_f = (const float*)d_in[5];
  const float* Whh_f = (const float*)d_in[6];
  const float* b_f   = (const float*)d_in[7];
  const float* Wih_b = (const float*)d_in[8];
  const float* Whh_b = (const float*)d_in[9];
  const float* b_b   = (const float*)d_in[10];
  const float* Wred  = (const float*)d_in[11];
  const float* bred  = (const float*)d_in[12];
  const float* Wef   = (const float*)d_in[13];
  const float* bef   = (const float*)d_in[14];
  const float* vvec  = (const float*)d_in[15];
  const float* Wx    = (const float*)d_in[16];
  const float* bx    = (const float*)d_in[17];
  const float* Wih_d = (const float*)d_in[18];
  const float* Whh_d = (const float*)d_in[19];
  const float* b_d   = (const float*)d_in[20];
  const float* Wdf   = (const float*)d_in[21];
  const float* bdf   = (const float*)d_in[22];
  const float* Wpg   = (const float*)d_in[23];
  const float* bpg   = (const float*)d_in[24];
  const float* Wout  = (const float*)d_in[25];
  const float* bout  = (const float*)d_in[26];
  const float* Wv    = (const float*)d_in[27];
  const float* bv    = (const float*)d_in[28];
  float* out = (float*)d_out;
  float* wsf = (float*)d_ws;
  float* dob = out;   // d_out used as scratch until k5a overwrites it

  k0_wcg<<<dim3(16, 8), 256, 0, stream>>>(Wx, Wih_d, dob, wsf);
  k1d_dec_pre<<<100, 256, 0, stream>>>(dtok, emb, Wx, bx, Wih_d, b_d, dob);

  {
    void* args2[9] = {(void*)&etok, (void*)&emb, (void*)&Wih_f, (void*)&b_f,
                      (void*)&Wih_b, (void*)&b_b, (void*)&Whh_f, (void*)&Whh_b, (void*)&wsf};
    if (hipLaunchCooperativeKernel((void*)k2_encoder_scan, dim3(64), dim3(256), args2, 0, stream) != hipSuccess)
      k2_encoder_scan<<<64, 256, 0, stream>>>(etok, emb, Wih_f, b_f, Wih_b, b_b, Whh_f, Whh_b, wsf);
  }

  k3_encfeat<<<dim3(10, 50), 256, 0, stream>>>(wsf + OFS_EO, Wef, bef, wsf + OFS_EF);
  k3b_eowt<<<dim3(16, 10, 8), 256, 0, stream>>>(wsf + OFS_EO, dob, dob);

  {
    void* args4[9] = {(void*)&maskp, (void*)&Wred, (void*)&bred, (void*)&Whh_d,
                      (void*)&Wdf, (void*)&bdf, (void*)&vvec, (void*)&wsf, (void*)&dob};
    if (hipLaunchCooperativeKernel((void*)k4_decoder, dim3(128), dim3(512), args4, 0, stream) != hipSuccess)
      k4_decoder<<<128, 512, 0, stream>>>(maskp, Wred, bred, Whh_d, Wdf, bdf, vvec, wsf, dob);
  }

  k4c_ctx<<<dim3(8, 2, 8), 256, 0, stream>>>(wsf, dob);
  k4b_post<<<100, 256, 0, stream>>>(Wx, Wout, bout, Wpg, bpg, wsf, dob);

  k5a_logits<<<dim3(13, 196), 256, 0, stream>>>(wsf + OFS_OUTS, Wv, bv, out);
  k5b_rowsum<<<800, 256, 0, stream>>>(out, wsf + OFS_SROW);
  k5c_final<<<dim3(25, 800), 256, 0, stream>>>(out, wsf + OFS_SROW, wsf + OFS_PG);
  k5d_scatter<<<800, 256, 0, stream>>>(out, wsf, ext);
}

// Round 10
// 3551.620 us; speedup vs baseline: 1.5023x; 1.5023x over previous
//
#include <hip/hip_runtime.h>

#define DEVI __device__ __forceinline__

// ---------------- problem constants ----------------
constexpr int B_ = 8, TE_ = 400, TD_ = 100, E_ = 128, H_ = 256;
constexpr int A_ = 612, V_ = 50000, VEXT_ = 50050;
constexpr int H4_ = 1024, H2_ = 512;
constexpr int NS_ = 16, SLW_ = 40;   // k4 a-slices: 15x40 + 1x12

// ---------------- workspace offsets (floats) ----------------
constexpr size_t OFS_HBF  = 0;            // fwd h state dbuf [2][256][8]
constexpr size_t OFS_HBB  = 4096;         // bwd h state dbuf
constexpr size_t OFS_CT   = 8192;         // [8][512] concat(cTf,cTb)
constexpr size_t OFS_CHC  = 12288;        // [2][8][512] decoder (h|c) dbuf
constexpr size_t OFS_PG   = 32896;        // [100][8] p_gen
constexpr size_t OFS_SROW = 33696;        // [800] vocab softmax denom
constexpr size_t OFS_FLG  = 34496;        // 1024 u32: k2f[0,128) k2b[128,256) k4full[256,512) k4grp[512,1024)
constexpr size_t OFS_ATT  = 35520;        // [100][8][400]
constexpr size_t OFS_EO   = 355520;       // [8][400][512] enc_out
constexpr size_t OFS_OUTS = OFS_EO;       // alias: k4b reuses eo buffer (eo dead after k4c)
constexpr size_t OFS_EF   = OFS_EO + (size_t)B_*TE_*H2_;   // [8][400][612]

// ---------------- d_out scratch offsets (floats) -- dead before k5a ----------------
constexpr size_t DO_GINF = 0;                                // [400][8][1024]
constexpr size_t DO_GINB = DO_GINF + (size_t)TE_*B_*H4_;     // [400][8][1024]
constexpr size_t DO_GDEC = 2ull*(size_t)TE_*B_*H4_;          // [100][8][1024]
constexpr size_t DO_XPRE = DO_GDEC + (size_t)TD_*B_*H4_;     // [100][8][128]
constexpr size_t DO_CTXH = DO_XPRE + (size_t)TD_*B_*E_;      // [100][8][512]
constexpr size_t DO_HCH  = DO_CTXH + (size_t)TD_*B_*H2_;     // [100][8][512] (h|c)
constexpr size_t DO_WCG  = DO_HCH + (size_t)TD_*B_*H2_;      // [512][1024]
constexpr size_t DO_EOWT = DO_WCG + (size_t)H2_*H4_;         // [8][1024][400] (eo@Wcg)^T
constexpr size_t DO_EPB  = DO_EOWT + (size_t)B_*H4_*TE_;     // [8][400][16] e-partials

// ---------------- helpers ----------------
#if defined(__has_builtin)
#if __has_builtin(__builtin_amdgcn_rcpf)
#define HAS_RCPF 1
#endif
#endif

DEVI float rcp_fast(float x) {
#ifdef HAS_RCPF
  return __builtin_amdgcn_rcpf(x);
#else
  return 1.0f / x;
#endif
}

DEVI float sigm(float x) { return rcp_fast(1.0f + __expf(-x)); }
DEVI float tanh_fast(float x) {
  float e = __expf(2.0f * x);
  return 1.0f - 2.0f * rcp_fast(e + 1.0f);
}

// ---- agent-coherent scalar accesses ----
DEVI float ld_at(const float* p) {
  unsigned u = __hip_atomic_load((const unsigned*)p, __ATOMIC_RELAXED, __HIP_MEMORY_SCOPE_AGENT);
  return __uint_as_float(u);
}
DEVI void st_at(float* p, float v) {
  __hip_atomic_store((unsigned*)p, __float_as_uint(v), __ATOMIC_RELAXED, __HIP_MEMORY_SCOPE_AGENT);
}

#define WAIT_VM() do { asm volatile("s_waitcnt vmcnt(0)" ::: "memory"); \
                       __builtin_amdgcn_sched_barrier(0); } while (0)

DEVI float wave_max(float v) {
#pragma unroll
  for (int o = 32; o; o >>= 1) v = fmaxf(v, __shfl_xor(v, o));
  return v;
}
DEVI float wave_sum(float v) {
#pragma unroll
  for (int o = 32; o; o >>= 1) v += __shfl_xor(v, o);
  return v;
}

// flag-array grid barrier (stride-parameterized), sleep backoff
DEVI void flag_bar(unsigned* flags, int ncheck, int slot, unsigned ep, int stride) {
  __syncthreads();
  if (threadIdx.x == 0) {
    asm volatile("s_waitcnt vmcnt(0)" ::: "memory");
    __hip_atomic_store(&flags[slot * stride], ep, __ATOMIC_RELAXED, __HIP_MEMORY_SCOPE_AGENT);
  }
  if ((int)threadIdx.x < ncheck) {
    while (__hip_atomic_load(&flags[threadIdx.x * stride], __ATOMIC_RELAXED,
                             __HIP_MEMORY_SCOPE_AGENT) < ep) {
      __builtin_amdgcn_s_sleep(2);
    }
  }
  __syncthreads();
  asm volatile("" ::: "memory");
}

// =====================================================================
// K0: Wcg[512][1024] = Wx[128:640] @ Wih_d ; block(0,0) zeroes h-state
//     + barrier flags (runs first on stream)
// =====================================================================
__global__ __launch_bounds__(256) void k0_wcg(
    const float* __restrict__ Wx, const float* __restrict__ Wih_d,
    float* __restrict__ dob, float* __restrict__ ws)
{
  __shared__ float AsT[32 * 64];
  __shared__ float Bsh[32 * 64];
  const float* Am = Wx + 128 * 128;
  float* C = dob + DO_WCG;
  const int ct = blockIdx.x, rt = blockIdx.y, tid = threadIdx.x;
  if (ct == 0 && rt == 0) {
    for (int i = tid; i < 8192; i += 256) ws[OFS_HBF + i] = 0.0f;
    unsigned* f = (unsigned*)(ws + OFS_FLG);
    for (int i = tid; i < 1024; i += 256) f[i] = 0u;
  }
  const int c0 = ct * 64, r0 = rt * 64;
  const int tx = tid & 15, ty = tid >> 4;
  float4 acc0 = make_float4(0,0,0,0), acc1 = acc0, acc2 = acc0, acc3 = acc0;
  for (int kc = 0; kc < 4; ++kc) {
#pragma unroll
    for (int i = 0; i < 2; ++i) {
      int q = tid * 2 + i;
      int r = q >> 3, kq = q & 7;
      float4 v = *(const float4*)&Am[(size_t)(r0 + r) * 128 + kc * 32 + kq * 4];
      AsT[(kq * 4 + 0) * 64 + r] = v.x; AsT[(kq * 4 + 1) * 64 + r] = v.y;
      AsT[(kq * 4 + 2) * 64 + r] = v.z; AsT[(kq * 4 + 3) * 64 + r] = v.w;
    }
#pragma unroll
    for (int i = 0; i < 2; ++i) {
      int q = tid * 2 + i;
      int kk = q >> 4, cq = q & 15;
      *(float4*)&Bsh[kk * 64 + cq * 4] =
          *(const float4*)&Wih_d[(size_t)(kc * 32 + kk) * H4_ + c0 + cq * 4];
    }
    __syncthreads();
#pragma unroll
    for (int kk = 0; kk < 32; ++kk) {
      float4 w4 = *(float4*)&Bsh[kk * 64 + tx * 4];
      const float* ar = &AsT[kk * 64 + ty * 4];
      acc0.x += ar[0]*w4.x; acc0.y += ar[0]*w4.y; acc0.z += ar[0]*w4.z; acc0.w += ar[0]*w4.w;
      acc1.x += ar[1]*w4.x; acc1.y += ar[1]*w4.y; acc1.z += ar[1]*w4.z; acc1.w += ar[1]*w4.w;
      acc2.x += ar[2]*w4.x; acc2.y += ar[2]*w4.y; acc2.z += ar[2]*w4.z; acc2.w += ar[2]*w4.w;
      acc3.x += ar[3]*w4.x; acc3.y += ar[3]*w4.y; acc3.z += ar[3]*w4.z; acc3.w += ar[3]*w4.w;
    }
    __syncthreads();
  }
  float4 r4[4] = {acc0, acc1, acc2, acc3};
#pragma unroll
  for (int i = 0; i < 4; ++i)
    *(float4*)&C[(size_t)(r0 + ty * 4 + i) * H4_ + c0 + tx * 4] = r4[i];
}

// =====================================================================
// K1: encoder embedding + input-gate precompute -> gin_f/gin_b in d_out
// =====================================================================
__global__ __launch_bounds__(256) void k1_embed_gates(
    const int* __restrict__ etok, const float* __restrict__ emb,
    const float* __restrict__ Wih_f, const float* __restrict__ b_f,
    const float* __restrict__ Wih_b, const float* __restrict__ b_b,
    float* __restrict__ gin_f, float* __restrict__ gin_b)
{
  __shared__ float er[8 * 128];
  const int t = blockIdx.x, tid = threadIdx.x;
  for (int i = tid; i < 1024; i += 256) {
    int b = i >> 7, e = i & 127;
    er[i] = emb[(size_t)etok[b * TE_ + t] * E_ + e];
  }
  __syncthreads();
  float bfv[4], bbv[4];
#pragma unroll
  for (int g = 0; g < 4; ++g) { bfv[g] = b_f[g * H_ + tid]; bbv[g] = b_b[g * H_ + tid]; }
  float af[32], ab[32];
#pragma unroll
  for (int i = 0; i < 32; ++i) { af[i] = bfv[i & 3]; ab[i] = bbv[i & 3]; }
  for (int e = 0; e < E_; ++e) {
    float wf[4], wb[4];
#pragma unroll
    for (int g = 0; g < 4; ++g) {
      wf[g] = Wih_f[(size_t)e * H4_ + g * H_ + tid];
      wb[g] = Wih_b[(size_t)e * H4_ + g * H_ + tid];
    }
#pragma unroll
    for (int b = 0; b < 8; ++b) {
      float x = er[b * 128 + e];
#pragma unroll
      for (int g = 0; g < 4; ++g) { af[b * 4 + g] += x * wf[g]; ab[b * 4 + g] += x * wb[g]; }
    }
  }
#pragma unroll
  for (int b = 0; b < 8; ++b)
#pragma unroll
    for (int g = 0; g < 4; ++g) {
      gin_f[((size_t)t * 8 + b) * H4_ + g * H_ + tid] = af[b * 4 + g];
      gin_b[((size_t)t * 8 + b) * H4_ + g * H_ + tid] = ab[b * 4 + g];
    }
}

// =====================================================================
// K1d: decoder precompute: xpre[t]=emb@WxE+bx, gdec[t]=xpre@Wih_d+b_d
// =====================================================================
__global__ __launch_bounds__(256) void k1d_dec_pre(
    const int* __restrict__ dtok, const float* __restrict__ emb,
    const float* __restrict__ Wx, const float* __restrict__ bx,
    const float* __restrict__ Wih_d, const float* __restrict__ b_d,
    float* __restrict__ dob)
{
  __shared__ float er[8 * 128];
  __shared__ float xl[8 * 128];
  const int t = blockIdx.x, tid = threadIdx.x;
  for (int i = tid; i < 1024; i += 256) {
    int b = i >> 7, e = i & 127;
    er[i] = emb[(size_t)dtok[b * TD_ + t] * E_ + e];
  }
  __syncthreads();
  {
    const int col = tid & 127, bh = tid >> 7;
#pragma unroll
    for (int ii = 0; ii < 4; ++ii) {
      int b = bh + (ii << 1);
      float acc = bx[col];
      for (int k = 0; k < 128; ++k) acc += er[b * 128 + k] * Wx[(size_t)k * E_ + col];
      xl[b * 128 + col] = acc;
      dob[DO_XPRE + ((size_t)t * 8 + b) * E_ + col] = acc;
    }
  }
  __syncthreads();
  float bv[4];
#pragma unroll
  for (int g = 0; g < 4; ++g) bv[g] = b_d[g * H_ + tid];
  float af[32];
#pragma unroll
  for (int i = 0; i < 32; ++i) af[i] = bv[i & 3];
  for (int e = 0; e < E_; ++e) {
    float w[4];
#pragma unroll
    for (int g = 0; g < 4; ++g) w[g] = Wih_d[(size_t)e * H4_ + g * H_ + tid];
#pragma unroll
    for (int b = 0; b < 8; ++b) {
      float x = xl[b * 128 + e];
#pragma unroll
      for (int g = 0; g < 4; ++g) af[b * 4 + g] += x * w[g];
    }
  }
#pragma unroll
  for (int b = 0; b < 8; ++b)
#pragma unroll
    for (int g = 0; g < 4; ++g)
      dob[DO_GDEC + ((size_t)t * 8 + b) * H4_ + g * H_ + tid] = af[b * 4 + g];
}

// =====================================================================
// K2: both encoder LSTM scans — 64 blocks x 256 thr (round-7 structure)
// =====================================================================
__global__ __launch_bounds__(256, 1) void k2_encoder_scan(
    const float* __restrict__ gin_f, const float* __restrict__ gin_b,
    const float* __restrict__ Whh_f, const float* __restrict__ Whh_b,
    float* __restrict__ ws)
{
  __shared__ float sm[4096];
  const int bid = blockIdx.x, tid = threadIdx.x;
  const int dir = bid >> 5, c0 = (bid & 31) * 8;
  const float* Whh = dir ? Whh_b : Whh_f;
  const float* gin = dir ? gin_b : gin_f;
  float* hb = ws + (dir ? OFS_HBB : OFS_HBF);
  float* cT = ws + OFS_CT;
  float* eo = ws + OFS_EO;
  unsigned* flg = (unsigned*)(ws + OFS_FLG) + (dir ? 128 : 0);
  const int slot = bid & 31;

  const int jl = tid >> 3, kg = tid & 7;
  const int gt = jl >> 3, hcl = jl & 7;
  const int jcol = gt * H_ + c0 + hcl;
  float wreg[32];
#pragma unroll
  for (int kk = 0; kk < 32; ++kk) wreg[kk] = Whh[(size_t)(kg + kk * 8) * H4_ + jcol];

  const int uhc = tid >> 3, ub = tid & 7;
  float c_reg = 0.0f;
  unsigned ep = 0;

  for (int t = 0; t < TE_; ++t) {
    const int te = dir ? (TE_ - 1 - t) : t;
    float* hrd = hb + (t & 1) * 2048;
    float* hwr = hb + ((t & 1) ^ 1) * 2048;
    float gpre[4] = {0, 0, 0, 0};
    if (tid < 64) {
#pragma unroll
      for (int gg = 0; gg < 4; ++gg)
        gpre[gg] = gin[((size_t)te * 8 + ub) * H4_ + gg * H_ + c0 + uhc];
    }
    {
      float4 v0, v1;
      const float* a0 = &hrd[tid * 8];
      const float* a1 = &hrd[tid * 8 + 4];
      asm volatile(
          "global_load_dwordx4 %0, %2, off sc0 sc1\n\t"
          "global_load_dwordx4 %1, %3, off sc0 sc1"
          : "=&v"(v0), "=&v"(v1) : "v"(a0), "v"(a1));
      WAIT_VM();
      *(float4*)&sm[tid * 8] = v0;
      *(float4*)&sm[tid * 8 + 4] = v1;
    }
    __syncthreads();
    float acc[8] = {0, 0, 0, 0, 0, 0, 0, 0};
#pragma unroll
    for (int kk = 0; kk < 32; ++kk) {
      float w = wreg[kk];
      const float* hp = &sm[(kg + kk * 8) * 8];
#pragma unroll
      for (int b = 0; b < 8; ++b) acc[b] += hp[b] * w;
    }
    float* part = sm + 2048;
    *(float4*)&part[(jl * 8 + kg) * 8]     = make_float4(acc[0], acc[1], acc[2], acc[3]);
    *(float4*)&part[(jl * 8 + kg) * 8 + 4] = make_float4(acc[4], acc[5], acc[6], acc[7]);
    __syncthreads();
    if (tid < 64) {
      float g[4];
#pragma unroll
      for (int gg = 0; gg < 4; ++gg) {
        float s = gpre[gg];
#pragma unroll
        for (int k2 = 0; k2 < 8; ++k2) s += part[((gg * 8 + uhc) * 8 + k2) * 8 + ub];
        g[gg] = s;
      }
      float ci = sigm(g[0]), cf = sigm(g[1]), cg = tanh_fast(g[2]), co = sigm(g[3]);
      c_reg = cf * c_reg + ci * cg;
      float hn = co * tanh_fast(c_reg);
      st_at(&hwr[(c0 + uhc) * 8 + ub], hn);
      eo[((size_t)ub * TE_ + te) * H2_ + dir * H_ + c0 + uhc] = hn;
      if (t == TE_ - 1) cT[ub * H2_ + dir * H_ + c0 + uhc] = c_reg;
    }
    ep++; flag_bar(flg, 32, slot, ep, 4);
  }
}

// =====================================================================
// K3: enc_feat = enc_out(3200,512) @ Wenc_feat(512,612) + benc_feat
// =====================================================================
__global__ __launch_bounds__(256) void k3_encfeat(
    const float* __restrict__ eo, const float* __restrict__ Wef,
    const float* __restrict__ bef, float* __restrict__ ef)
{
  __shared__ float AsT[32 * 64];
  __shared__ float Wsh[32 * 64];
  const int ct = blockIdx.x, rt = blockIdx.y, tid = threadIdx.x;
  const int c0 = ct * 64, r0 = rt * 64;
  const int tx = tid & 15, ty = tid >> 4;
  float4 acc0 = make_float4(0,0,0,0), acc1 = acc0, acc2 = acc0, acc3 = acc0;
  for (int kc = 0; kc < 16; ++kc) {
#pragma unroll
    for (int i = 0; i < 2; ++i) {
      int q = tid * 2 + i;
      int r = q >> 3, kq = q & 7;
      float4 v = *(const float4*)&eo[(size_t)(r0 + r) * H2_ + kc * 32 + kq * 4];
      AsT[(kq * 4 + 0) * 64 + r] = v.x; AsT[(kq * 4 + 1) * 64 + r] = v.y;
      AsT[(kq * 4 + 2) * 64 + r] = v.z; AsT[(kq * 4 + 3) * 64 + r] = v.w;
    }
#pragma unroll
    for (int i = 0; i < 2; ++i) {
      int q = tid * 2 + i;
      int kk = q >> 4, cq = q & 15;
      int col = c0 + cq * 4;
      float4 v = make_float4(0,0,0,0);
      if (col < A_) v = *(const float4*)&Wef[(size_t)(kc * 32 + kk) * A_ + col];
      *(float4*)&Wsh[kk * 64 + cq * 4] = v;
    }
    __syncthreads();
#pragma unroll
    for (int kk = 0; kk < 32; ++kk) {
      float4 w4 = *(float4*)&Wsh[kk * 64 + tx * 4];
      const float* ar = &AsT[kk * 64 + ty * 4];
      acc0.x += ar[0]*w4.x; acc0.y += ar[0]*w4.y; acc0.z += ar[0]*w4.z; acc0.w += ar[0]*w4.w;
      acc1.x += ar[1]*w4.x; acc1.y += ar[1]*w4.y; acc1.z += ar[1]*w4.z; acc1.w += ar[1]*w4.w;
      acc2.x += ar[2]*w4.x; acc2.y += ar[2]*w4.y; acc2.z += ar[2]*w4.z; acc2.w += ar[2]*w4.w;
      acc3.x += ar[3]*w4.x; acc3.y += ar[3]*w4.y; acc3.z += ar[3]*w4.z; acc3.w += ar[3]*w4.w;
    }
    __syncthreads();
  }
  const int col = c0 + tx * 4;
  if (col < A_) {
    float4 bb = *(const float4*)&bef[col];
    float4 r4[4] = {acc0, acc1, acc2, acc3};
#pragma unroll
    for (int i = 0; i < 4; ++i) {
      int row = r0 + ty * 4 + i;
      float4 o = make_float4(r4[i].x + bb.x, r4[i].y + bb.y, r4[i].z + bb.z, r4[i].w + bb.w);
      *(float4*)&ef[(size_t)row * A_ + col] = o;
    }
  }
}

// =====================================================================
// K3b: eoWT[b][j][te] = sum_k eo[b][te][k] * Wcg[k][j]
// =====================================================================
__global__ __launch_bounds__(256) void k3b_eowt(
    const float* __restrict__ eo, const float* __restrict__ dob_c, float* __restrict__ dob)
{
  __shared__ float Wt[32 * 64];
  __shared__ float Et[32 * 40];
  const float* Wcg = dob_c + DO_WCG;
  float* eoWT = dob + DO_EOWT;
  const int jt = blockIdx.x, tt = blockIdx.y, b = blockIdx.z, tid = threadIdx.x;
  const int j0 = jt * 64, te0 = tt * 40;
  const int j_l = tid & 63, tq = tid >> 6;
  float acc[10];
#pragma unroll
  for (int u = 0; u < 10; ++u) acc[u] = 0.0f;
  for (int kc = 0; kc < 16; ++kc) {
#pragma unroll
    for (int i = 0; i < 2; ++i) {
      int q = tid * 2 + i;
      int kk = q >> 4, j4 = q & 15;
      *(float4*)&Wt[kk * 64 + j4 * 4] =
          *(const float4*)&Wcg[(size_t)(kc * 32 + kk) * H4_ + j0 + j4 * 4];
    }
#pragma unroll
    for (int i = 0; i < 2; ++i) {
      int q = tid + i * 256;
      if (q < 320) {
        int te_l = q >> 3, kq = q & 7;
        float4 v = *(const float4*)&eo[((size_t)b * TE_ + te0 + te_l) * H2_ + kc * 32 + kq * 4];
        Et[(kq * 4 + 0) * 40 + te_l] = v.x; Et[(kq * 4 + 1) * 40 + te_l] = v.y;
        Et[(kq * 4 + 2) * 40 + te_l] = v.z; Et[(kq * 4 + 3) * 40 + te_l] = v.w;
      }
    }
    __syncthreads();
#pragma unroll
    for (int kk = 0; kk < 32; ++kk) {
      float w = Wt[kk * 64 + j_l];
      const float* ep2 = &Et[kk * 40 + tq * 10];
#pragma unroll
      for (int u = 0; u < 10; ++u) acc[u] += w * ep2[u];
    }
    __syncthreads();
  }
  float* outp = &eoWT[((size_t)b * H4_ + j0 + j_l) * TE_ + te0 + tq * 10];
#pragma unroll
  for (int u = 0; u < 10; ++u) outp[u] = acc[u];
}

// =====================================================================
// K4: decoder — 128 blocks x 512 thr, block=(b, s16). 2 group-barriers/step.
// =====================================================================
__global__ __launch_bounds__(512, 1) void k4_decoder(
    const float* __restrict__ maskp,
    const float* __restrict__ Wred, const float* __restrict__ bred,
    const float* __restrict__ Whh_d,
    const float* __restrict__ Wdf, const float* __restrict__ bdf,
    const float* __restrict__ vvec, float* __restrict__ ws, float* __restrict__ dob)
{
  __shared__ float eoW[TE_ * 64];     // [te][jg] 102.4 KB
  __shared__ float eu[TE_];
  __shared__ float hcL[512];
  __shared__ float red[16];
  __shared__ float gdL[64];
  __shared__ float gl[64];
  __shared__ float pgl[64 * 9];
  __shared__ float prt[1280];
  __shared__ float dfl[48];
  __shared__ float bdfL[48];
  __shared__ float vvL[48];

  float* chc = ws + OFS_CHC;
  float* att = ws + OFS_ATT;
  const float* efG = ws + OFS_EF;
  const float* hbf = ws + OFS_HBF;
  const float* hbb = ws + OFS_HBB;
  const float* cT  = ws + OFS_CT;
  unsigned* flgF = (unsigned*)(ws + OFS_FLG) + 256;           // full: 128 slots, stride 2
  const float* gdec = dob + DO_GDEC;
  const float* eoWT = dob + DO_EOWT;
  float* epb = dob + DO_EPB;
  float* hch = dob + DO_HCH;
  const int bid = blockIdx.x, tid = threadIdx.x;
  const int b = bid >> 4, s = bid & 15;
  unsigned* flgG = (unsigned*)(ws + OFS_FLG) + 512 + b * 64;  // group: 16 slots, stride 4
  const int a0 = s * SLW_, w = (s == 15) ? 12 : SLW_;
  const int nq = w >> 2;

  // ---- one-time fills: eoW LDS slice, Whh regs, vvec slice ----
  for (int i = tid; i < 64 * 100; i += 512) {
    int jgi = i / 100, c = i - jgi * 100;
    int jreal = (jgi >> 4) * 256 + s * 16 + (jgi & 15);
    float4 v = *(const float4*)&eoWT[((size_t)b * H4_ + jreal) * TE_ + c * 4];
    eoW[(c * 4 + 0) * 64 + jgi] = v.x;
    eoW[(c * 4 + 1) * 64 + jgi] = v.y;
    eoW[(c * 4 + 2) * 64 + jgi] = v.z;
    eoW[(c * 4 + 3) * 64 + jgi] = v.w;
  }
  const int jg = tid & 63, l8 = tid >> 6;
  const int jreal = (jg >> 4) * 256 + s * 16 + (jg & 15);
  float wreg[32];
#pragma unroll
  for (int kk = 0; kk < 32; ++kk)
    wreg[kk] = Whh_d[(size_t)(l8 + kk * 8) * H4_ + jreal];
  if (tid < w) vvL[tid] = vvec[a0 + tid];

  // ---- P0: h0/c0 (blocks 0..31); Wdf[0] prefetch (32..127) ----
  if (bid < 32) {
    const int isC = bid >> 4, pb = (bid >> 1) & 7, half = bid & 1;
    if (tid < 512)
      hcL[tid] = isC ? cT[pb * H2_ + tid]
                     : (tid < H_ ? hbf[tid * 8 + pb] : hbb[(tid - H_) * 8 + pb]);
    __syncthreads();
    {
      const int col_l = tid & 127, ks = tid >> 7;
      float acc = 0.0f;
      for (int kk = 0; kk < 128; ++kk) {
        int k = ks * 128 + kk;
        acc += hcL[k] * Wred[(size_t)k * H_ + half * 128 + col_l];
      }
      prt[ks * 128 + col_l] = acc;
    }
    __syncthreads();
    if (tid < 128) {
      float v2 = fmaxf(prt[tid] + prt[128 + tid] + prt[256 + tid] + prt[384 + tid] +
                       bred[half * 128 + tid], 0.0f);
      st_at(&chc[pb * H2_ + isC * H_ + half * 128 + tid], v2);
    }
  } else {
    float dm = 0.0f;
#pragma unroll
    for (int i = 0; i < 7; ++i) {
      int f = (bid - 32) * 3264 + i * 512 + tid;
      if (i * 512 + tid < 3264 && f < H2_ * A_) dm += Wdf[f];
    }
    asm volatile("" :: "v"(dm));
  }
  unsigned ep = 1;
  flag_bar(flgF, 128, bid, ep, 2);

  float c_reg = 0.0f;
  if (tid < 16) c_reg = ld_at(&chc[b * H2_ + H_ + s * 16 + tid]);
  unsigned epg = 0;

  // ---- main loop ----
  for (int t = 0; t <= TD_; ++t) {
    const int cur = t & 1, nxt = cur ^ 1;

    // ===== P1 =====
    {
      // batched coherent stage: epb(4xf4), h(1xf4 tid<64), gdec(1xf4 tid<16)
      const int teA = (tid < TE_) ? tid : TE_ - 1;
      const int tcl = (t < TD_) ? t : TD_ - 1;
      const float* ae = &epb[((size_t)b * TE_ + teA) * 16];
      const float* ah = &chc[cur * 4096 + b * H2_ + (tid & 63) * 4];
      const int gi = tid & 15;
      const float* agd = &gdec[((size_t)tcl * 8 + b) * H4_ +
                               (gi >> 2) * 256 + s * 16 + (gi & 3) * 4];
      float4 v0, v1, v2, v3, vh, vgd;
      asm volatile(
          "global_load_dwordx4 %0, %6, off sc0 sc1\n\t"
          "global_load_dwordx4 %1, %7, off sc0 sc1\n\t"
          "global_load_dwordx4 %2, %8, off sc0 sc1\n\t"
          "global_load_dwordx4 %3, %9, off sc0 sc1\n\t"
          "global_load_dwordx4 %4, %10, off sc0 sc1\n\t"
          "global_load_dwordx4 %5, %11, off sc0 sc1"
          : "=&v"(v0), "=&v"(v1), "=&v"(v2), "=&v"(v3), "=&v"(vh), "=&v"(vgd)
          : "v"(ae), "v"(ae + 4), "v"(ae + 8), "v"(ae + 12), "v"(ah), "v"(agd));
      WAIT_VM();
      if (t > 0 && tid < TE_)
        eu[tid] = (v0.x + v0.y + v0.z + v0.w) + (v1.x + v1.y + v1.z + v1.w) +
                  (v2.x + v2.y + v2.z + v2.w) + (v3.x + v3.y + v3.z + v3.w);
      if (tid < 64) *(float4*)&hcL[tid * 4] = vh;
      if (tid < 16) *(float4*)&gdL[(gi >> 2) * 16 + (gi & 3) * 4] = vgd;
      __syncthreads();

      float inv = 0.0f;
      if (t > 0) {
        float m = (tid < TE_) ? eu[tid] : -3.4e38f;
        m = wave_max(m);
        if ((tid & 63) == 0) red[tid >> 6] = m;
        __syncthreads();
        m = red[0];
#pragma unroll
        for (int i = 1; i < 8; ++i) m = fmaxf(m, red[i]);
        float u = 0.0f;
        if (tid < TE_) {
          u = __expf(eu[tid] - m) * maskp[b * TE_ + tid];
          eu[tid] = u;
        }
        float sl = wave_sum(u);
        if ((tid & 63) == 0) red[8 + (tid >> 6)] = sl;
        __syncthreads();
        float S = 0.0f;
#pragma unroll
        for (int i = 0; i < 8; ++i) S += red[8 + i];
        inv = rcp_fast(S);
      }

      // spread att write across all 16 slice-blocks (25 te each)
      if (t > 0 && tid < 25)
        att[((size_t)(t - 1) * 8 + b) * TE_ + s * 25 + tid] = eu[s * 25 + tid] * inv;

      if (t < TD_) {
        float accG = 0.0f, accW = 0.0f;
        if (t > 0) {
          for (int te = l8; te < TE_; te += 8)
            accG += eoW[te * 64 + jg] * eu[te];
        }
#pragma unroll
        for (int kk = 0; kk < 32; ++kk)
          accW += wreg[kk] * hcL[l8 + kk * 8];
        pgl[jg * 9 + l8] = accG * inv + accW;
        __syncthreads();
        if (tid < 64) {
          float sg = gdL[tid];
#pragma unroll
          for (int l = 0; l < 8; ++l) sg += pgl[tid * 9 + l];
          gl[tid] = sg;
        }
        __syncthreads();
        if (tid < 16) {
          float g0 = gl[tid], g1 = gl[16 + tid], g2 = gl[32 + tid], g3 = gl[48 + tid];
          float ci = sigm(g0), cf = sigm(g1), cg = tanh_fast(g2), co = sigm(g3);
          c_reg = cf * c_reg + ci * cg;
          float hn = co * tanh_fast(c_reg);
          int hc = s * 16 + tid;
          st_at(&chc[nxt * 4096 + b * H2_ + hc], hn);
          st_at(&chc[nxt * 4096 + b * H2_ + H_ + hc], c_reg);
          hch[((size_t)t * 8 + b) * H2_ + hc] = hn;
          hch[((size_t)t * 8 + b) * H2_ + H_ + hc] = c_reg;
        }
      }
    }
    if (t == TD_) break;
    epg++; flag_bar(flgG, 16, s, epg, 4);

    // ===== P2: decf a-slice + e-partials =====
    {
      // stage full hc(512) + bdf slice
      {
        const float* ahc = &chc[nxt * 4096 + b * H2_ + (tid & 127) * 4];
        const int cl = (tid < 10) ? tid : 9;
        const float* abf = &bdf[(size_t)t * A_ + a0 + cl * 4];
        float4 vhc, vbf;
        asm volatile(
            "global_load_dwordx4 %0, %2, off sc0 sc1\n\t"
            "global_load_dwordx4 %1, %3, off sc0 sc1"
            : "=&v"(vhc), "=&v"(vbf) : "v"(ahc), "v"(abf));
        WAIT_VM();
        if (tid < 128) *(float4*)&hcL[tid * 4] = vhc;
        if (tid < 10) *(float4*)&bdfL[tid * 4] = vbf;
      }
      __syncthreads();

      // decf partials: (kq 32 x al 16), al<nq active
      const float* wp = Wdf + (size_t)t * H2_ * A_;
      {
        const int kq = tid >> 4, al = tid & 15;
        if (al < nq) {
          float4 a4 = make_float4(0, 0, 0, 0);
          const float* wpc = wp + a0 + al * 4;
#pragma unroll
          for (int i = 0; i < 16; ++i) {
            int k = kq * 16 + i;
            float4 w4 = *(const float4*)&wpc[(size_t)k * A_];
            float hv = hcL[k];
            a4.x += hv * w4.x; a4.y += hv * w4.y; a4.z += hv * w4.z; a4.w += hv * w4.w;
          }
          *(float4*)&prt[(kq * 10 + al) * 4] = a4;
        }
      }
      // narrow prefetch of Wdf[t+1]: rows b*64..+63 x own a-slice
      float dm = 0.0f;
      if (t + 1 < TD_) {
        const float* wp1 = Wdf + (size_t)(t + 1) * H2_ * A_;
#pragma unroll
        for (int q = 0; q < 2; ++q) {
          int f = tid + q * 512;
          if (f < 640) {
            int r = f / 10, c4 = f - r * 10;
            if (c4 < nq) {
              float4 vx = *(const float4*)&wp1[(size_t)(b * 64 + r) * A_ + a0 + c4 * 4];
              dm += vx.x + vx.y + vx.z + vx.w;
            }
          }
        }
      }
      __syncthreads();
      if (tid < w) {
        float ssum = bdfL[tid];
        const int c4 = tid >> 2, r = tid & 3;
#pragma unroll
        for (int kq = 0; kq < 32; ++kq) ssum += prt[(kq * 10 + c4) * 4 + r];
        dfl[tid] = ssum;
      }
      __syncthreads();

      // e-partials: thread te = tid (<400)
      if (tid < TE_) {
        const float* efp = &efG[((size_t)b * TE_ + tid) * A_ + a0];
        float acc = 0.0f;
        for (int q = 0; q < nq; ++q) {
          float4 e4 = *(const float4*)&efp[q * 4];
          const float* dd = &dfl[q * 4];
          const float* vv = &vvL[q * 4];
          acc += vv[0] * tanh_fast(e4.x + dd[0]);
          acc += vv[1] * tanh_fast(e4.y + dd[1]);
          acc += vv[2] * tanh_fast(e4.z + dd[2]);
          acc += vv[3] * tanh_fast(e4.w + dd[3]);
        }
        st_at(&epb[((size_t)b * TE_ + tid) * 16 + s], acc);
      }
      asm volatile("" :: "v"(dm));
    }
    epg++; flag_bar(flgG, 16, s, epg, 4);
  }
}

// =====================================================================
// K4c: ctxh[t][b][d] = sum_te att[t][b][te] * eo[b][te][d]
// =====================================================================
__global__ __launch_bounds__(256) void k4c_ctx(
    const float* __restrict__ ws, float* __restrict__ dob)
{
  __shared__ float AsT[32 * 64];
  __shared__ float Bsh[32 * 64];
  const float* att = ws + OFS_ATT;
  const float* eo  = ws + OFS_EO;
  float* ctxh = dob + DO_CTXH;
  const int ct = blockIdx.x, rt = blockIdx.y, b = blockIdx.z, tid = threadIdx.x;
  const int c0 = ct * 64, r0 = rt * 64;
  const int tx = tid & 15, ty = tid >> 4;
  float4 acc0 = make_float4(0,0,0,0), acc1 = acc0, acc2 = acc0, acc3 = acc0;
  for (int kc = 0; kc < 13; ++kc) {
#pragma unroll
    for (int i = 0; i < 2; ++i) {
      int q = tid * 2 + i;
      int r = q >> 3, kq = q & 7;
      int k = kc * 32 + kq * 4;
      float4 v = make_float4(0, 0, 0, 0);
      if (k < TE_ && r0 + r < TD_)
        v = *(const float4*)&att[((size_t)(r0 + r) * 8 + b) * TE_ + k];
      AsT[(kq * 4 + 0) * 64 + r] = v.x; AsT[(kq * 4 + 1) * 64 + r] = v.y;
      AsT[(kq * 4 + 2) * 64 + r] = v.z; AsT[(kq * 4 + 3) * 64 + r] = v.w;
    }
#pragma unroll
    for (int i = 0; i < 2; ++i) {
      int q = tid * 2 + i;
      int kk = q >> 4, cq = q & 15;
      int k = kc * 32 + kk;
      float4 v = make_float4(0, 0, 0, 0);
      if (k < TE_) v = *(const float4*)&eo[((size_t)b * TE_ + k) * H2_ + c0 + cq * 4];
      *(float4*)&Bsh[kk * 64 + cq * 4] = v;
    }
    __syncthreads();
#pragma unroll
    for (int kk = 0; kk < 32; ++kk) {
      float4 w4 = *(float4*)&Bsh[kk * 64 + tx * 4];
      const float* ar = &AsT[kk * 64 + ty * 4];
      acc0.x += ar[0]*w4.x; acc0.y += ar[0]*w4.y; acc0.z += ar[0]*w4.z; acc0.w += ar[0]*w4.w;
      acc1.x += ar[1]*w4.x; acc1.y += ar[1]*w4.y; acc1.z += ar[1]*w4.z; acc1.w += ar[1]*w4.w;
      acc2.x += ar[2]*w4.x; acc2.y += ar[2]*w4.y; acc2.z += ar[2]*w4.z; acc2.w += ar[2]*w4.w;
      acc3.x += ar[3]*w4.x; acc3.y += ar[3]*w4.y; acc3.z += ar[3]*w4.z; acc3.w += ar[3]*w4.w;
    }
    __syncthreads();
  }
  float4 r4[4] = {acc0, acc1, acc2, acc3};
#pragma unroll
  for (int i = 0; i < 4; ++i) {
    int row = r0 + ty * 4 + i;
    if (row < TD_)
      *(float4*)&ctxh[((size_t)row * 8 + b) * H2_ + c0 + tx * 4] = r4[i];
  }
}

// =====================================================================
// K4b: batched post-pass: x_t, outs_t, p_gen_t for all t (grid 100)
// =====================================================================
__global__ __launch_bounds__(256) void k4b_post(
    const float* __restrict__ Wx, const float* __restrict__ Wout, const float* __restrict__ bout,
    const float* __restrict__ Wpg, const float* __restrict__ bpg,
    float* __restrict__ ws, const float* __restrict__ dob)
{
  __shared__ float hcl[4096], ctxl[4096], cpl[4096], xl[1024], red2[256];
  const int t = blockIdx.x, tid = threadIdx.x;
  const float* hch  = dob + DO_HCH;
  const float* ctxh = dob + DO_CTXH;
  const float* xpre = dob + DO_XPRE;
  for (int i = tid; i < 4096; i += 256) {
    hcl[i]  = hch[(size_t)t * 4096 + i];
    ctxl[i] = ctxh[(size_t)t * 4096 + i];
    cpl[i]  = t ? ctxh[(size_t)(t - 1) * 4096 + i] : 0.0f;
  }
  __syncthreads();
  {
    const int col = tid & 127, bh = tid >> 7;
#pragma unroll
    for (int ii = 0; ii < 4; ++ii) {
      int b = bh + (ii << 1);
      float acc = xpre[(size_t)t * 1024 + b * E_ + col];
      for (int k = 0; k < H2_; ++k) acc += cpl[b * H2_ + k] * Wx[(size_t)(128 + k) * E_ + col];
      xl[b * E_ + col] = acc;
    }
  }
  __syncthreads();
  {
    const int col = tid;
    for (int b = 0; b < 8; ++b) {
      float acc = bout[col];
      for (int k = 0; k < 768; ++k)
        acc += (k < H_ ? hcl[b * H2_ + k] : ctxl[b * H2_ + (k - H_)]) * Wout[(size_t)k * H_ + col];
      ws[OFS_OUTS + ((size_t)t * 8 + b) * H_ + col] = acc;
    }
  }
  {
    const int b = tid >> 5, sg = tid & 31;
    float acc = 0.0f;
    for (int j = 0; j < 36; ++j) {
      int k = sg * 36 + j;
      float xv;
      if (k < H2_)       xv = ctxl[b * H2_ + k];
      else if (k < 768)  xv = hcl[b * H2_ + (k - H2_)];
      else if (k < 1024) xv = hcl[b * H2_ + H_ + (k - 768)];
      else               xv = xl[b * E_ + (k - 1024)];
      acc += xv * Wpg[k];
    }
    red2[tid] = acc;
    __syncthreads();
    if (tid < 8) {
      float s = 0.0f;
      for (int k2 = 0; k2 < 32; ++k2) s += red2[tid * 32 + k2];
      ws[OFS_PG + t * 8 + tid] = sigm(s + bpg[0]);
    }
  }
}

// =====================================================================
// K5a: logits = outs(800,256) @ Wv(256,50000) + bv -> d_out
// grid (13 row-tiles, 196 col-tiles): row-tiles of one col-tile adjacent
// =====================================================================
__global__ __launch_bounds__(256) void k5a_logits(
    const float* __restrict__ outs, const float* __restrict__ Wv,
    const float* __restrict__ bv, float* __restrict__ out)
{
  __shared__ float aT[32 * 64];
  __shared__ float wl[32 * 256];
  const int rt = blockIdx.x, ct = blockIdx.y, tid = threadIdx.x;
  const int r0 = rt * 64, c0 = ct * 256;
  const int cq = tid & 63, rg = tid >> 6;
  float4 acc[16];
#pragma unroll
  for (int i = 0; i < 16; ++i) acc[i] = make_float4(0, 0, 0, 0);
  for (int kc = 0; kc < 8; ++kc) {
#pragma unroll
    for (int i = 0; i < 2; ++i) {
      int q = tid * 2 + i;
      int r = q >> 3, kq = q & 7;
      float4 v = make_float4(0, 0, 0, 0);
      if (r0 + r < 800) v = *(const float4*)&outs[(size_t)(r0 + r) * H_ + kc * 32 + kq * 4];
      aT[(kq * 4 + 0) * 64 + r] = v.x; aT[(kq * 4 + 1) * 64 + r] = v.y;
      aT[(kq * 4 + 2) * 64 + r] = v.z; aT[(kq * 4 + 3) * 64 + r] = v.w;
    }
#pragma unroll
    for (int i = 0; i < 8; ++i) {
      int q = tid + i * 256;
      int kk = q >> 6, c4 = q & 63;
      int col = c0 + c4 * 4;
      float4 v = make_float4(0, 0, 0, 0);
      if (col < V_) v = *(const float4*)&Wv[(size_t)(kc * 32 + kk) * V_ + col];
      *(float4*)&wl[kk * 256 + c4 * 4] = v;
    }
    __syncthreads();
#pragma unroll
    for (int kk = 0; kk < 32; ++kk) {
      float4 w4 = *(float4*)&wl[kk * 256 + cq * 4];
      const float* ar = &aT[kk * 64 + rg * 16];
#pragma unroll
      for (int rr = 0; rr < 16; ++rr) {
        float a = ar[rr];
        acc[rr].x += a * w4.x; acc[rr].y += a * w4.y;
        acc[rr].z += a * w4.z; acc[rr].w += a * w4.w;
      }
    }
    __syncthreads();
  }
  const int col = c0 + cq * 4;
  if (col < V_) {
    float4 bb = *(const float4*)&bv[col];
#pragma unroll
    for (int rr = 0; rr < 16; ++rr) {
      int row = r0 + rg * 16 + rr;
      if (row < 800) {
        float2 lo = make_float2(acc[rr].x + bb.x, acc[rr].y + bb.y);
        float2 hi = make_float2(acc[rr].z + bb.z, acc[rr].w + bb.w);
        *(float2*)&out[(size_t)row * VEXT_ + col] = lo;
        *(float2*)&out[(size_t)row * VEXT_ + col + 2] = hi;
      }
    }
  }
}

// K5b: per-row sum of exp(logit)
__global__ __launch_bounds__(256) void k5b_rowsum(const float* __restrict__ out, float* __restrict__ Srow)
{
  __shared__ float red[256];
  const int r = blockIdx.x, tid = threadIdx.x;
  const float* base = out + (size_t)r * VEXT_;
  float s = 0.0f;
  for (int i = tid; i < V_ / 2; i += 256) {
    float2 v = *(const float2*)&base[i * 2];
    s += __expf(v.x) + __expf(v.y);
  }
  red[tid] = s; __syncthreads();
  for (int st = 128; st > 0; st >>= 1) { if (tid < st) red[tid] += red[tid + st]; __syncthreads(); }
  if (tid == 0) Srow[r] = red[0];
}

// K5c: in-place final = pgen * exp(logit)/S ; zero OOV tail
__global__ __launch_bounds__(256) void k5c_final(
    float* __restrict__ out, const float* __restrict__ Srow, const float* __restrict__ pg)
{
  const int cc = blockIdx.x, r = blockIdx.y, tid = threadIdx.x;
  const float scale = pg[r] * rcp_fast(Srow[r]);
  float* base = out + (size_t)r * VEXT_;
#pragma unroll
  for (int i = 0; i < 4; ++i) {
    int col = cc * 2048 + i * 512 + tid * 2;
    if (col < V_) {
      float2 v = *(float2*)&base[col];
      v.x = __expf(v.x) * scale; v.y = __expf(v.y) * scale;
      *(float2*)&base[col] = v;
    } else if (col < VEXT_) {
      *(float2*)&base[col] = make_float2(0.0f, 0.0f);
    }
  }
}

// K5d: scatter copy distribution
__global__ __launch_bounds__(256) void k5d_scatter(
    float* __restrict__ out, const float* __restrict__ ws, const int* __restrict__ ext)
{
  const int r = blockIdx.x, tid = threadIdx.x;
  const int b = r & 7;
  const float* at = ws + OFS_ATT + (size_t)r * TE_;
  const float w = 1.0f - ws[OFS_PG + r];
  float* base = out + (size_t)r * VEXT_;
  for (int i = tid; i < TE_; i += 256)
    atomicAdd(&base[ext[b * TE_ + i]], w * at[i]);
}

// =====================================================================
extern "C" void kernel_launch(void* const* d_in, const int* in_sizes, int n_in,
                              void* d_out, int out_size, void* d_ws, size_t ws_size,
                              hipStream_t stream) {
  const int*   etok  = (const int*)d_in[0];
  const int*   dtok  = (const int*)d_in[1];
  const int*   ext   = (const int*)d_in[2];
  const float* maskp = (const float*)d_in[3];
  const float* emb   = (const float*)d_in[4];
  const float* Wih_f = (const float*)d_in[5];
  const float* Whh_f = (const float*)d_in[6];
  const float* b_f   = (const float*)d_in[7];
  const float* Wih_b = (const float*)d_in[8];
  const float* Whh_b = (const float*)d_in[9];
  const float* b_b   = (const float*)d_in[10];
  const float* Wred  = (const float*)d_in[11];
  const float* bred  = (const float*)d_in[12];
  const float* Wef   = (const float*)d_in[13];
  const float* bef   = (const float*)d_in[14];
  const float* vvec  = (const float*)d_in[15];
  const float* Wx    = (const float*)d_in[16];
  const float* bx    = (const float*)d_in[17];
  const float* Wih_d = (const float*)d_in[18];
  const float* Whh_d = (const float*)d_in[19];
  const float* b_d   = (const float*)d_in[20];
  const float* Wdf   = (const float*)d_in[21];
  const float* bdf   = (const float*)d_in[22];
  const float* Wpg   = (const float*)d_in[23];
  const float* bpg   = (const float*)d_in[24];
  const float* Wout  = (const float*)d_in[25];
  const float* bout  = (const float*)d_in[26];
  const float* Wv    = (const float*)d_in[27];
  const float* bv    = (const float*)d_in[28];
  float* out = (float*)d_out;
  float* wsf = (float*)d_ws;
  float* dob = out;   // d_out used as scratch until k5a overwrites it

  float* gin_f = dob + DO_GINF;
  float* gin_b = dob + DO_GINB;

  k0_wcg<<<dim3(16, 8), 256, 0, stream>>>(Wx, Wih_d, dob, wsf);
  k1_embed_gates<<<400, 256, 0, stream>>>(etok, emb, Wih_f, b_f, Wih_b, b_b, gin_f, gin_b);
  k1d_dec_pre<<<100, 256, 0, stream>>>(dtok, emb, Wx, bx, Wih_d, b_d, dob);

  {
    void* args2[5] = {(void*)&gin_f, (void*)&gin_b, (void*)&Whh_f, (void*)&Whh_b, (void*)&wsf};
    if (hipLaunchCooperativeKernel((void*)k2_encoder_scan, dim3(64), dim3(256), args2, 0, stream) != hipSuccess)
      k2_encoder_scan<<<64, 256, 0, stream>>>(gin_f, gin_b, Whh_f, Whh_b, wsf);
  }

  k3_encfeat<<<dim3(10, 50), 256, 0, stream>>>(wsf + OFS_EO, Wef, bef, wsf + OFS_EF);
  k3b_eowt<<<dim3(16, 10, 8), 256, 0, stream>>>(wsf + OFS_EO, dob, dob);

  {
    void* args4[9] = {(void*)&maskp, (void*)&Wred, (void*)&bred, (void*)&Whh_d,
                      (void*)&Wdf, (void*)&bdf, (void*)&vvec, (void*)&wsf, (void*)&dob};
    if (hipLaunchCooperativeKernel((void*)k4_decoder, dim3(128), dim3(512), args4, 0, stream) != hipSuccess)
      k4_decoder<<<128, 512, 0, stream>>>(maskp, Wred, bred, Whh_d, Wdf, bdf, vvec, wsf, dob);
  }

  k4c_ctx<<<dim3(8, 2, 8), 256, 0, stream>>>(wsf, dob);
  k4b_post<<<100, 256, 0, stream>>>(Wx, Wout, bout, Wpg, bpg, wsf, dob);

  k5a_logits<<<dim3(13, 196), 256, 0, stream>>>(wsf + OFS_OUTS, Wv, bv, out);
  k5b_rowsum<<<800, 256, 0, stream>>>(out, wsf + OFS_SROW);
  k5c_final<<<dim3(25, 800), 256, 0, stream>>>(out, wsf + OFS_SROW, wsf + OFS_PG);
  k5d_scatter<<<800, 256, 0, stream>>>(out, wsf, ext);
}